// Round 4
// baseline (152.424 us; speedup 1.0000x reference)
//
#include <hip/hip_runtime.h>

#define NBLOCKS 2048
#define NTHREADS 256
#define UNROLL 4
#define NUM_LEVELS 101

typedef float vfloat4 __attribute__((ext_vector_type(4)));

__global__ __launch_bounds__(NTHREADS) void wmse_fused(
    const float* __restrict__ x,
    const float* __restrict__ y,
    const float* __restrict__ wt,
    float* __restrict__ out, int n, float inv_n)
{
    __shared__ float s_wt[NUM_LEVELS];
    __shared__ float s_red[NTHREADS / 64];

    for (int i = threadIdx.x; i < NUM_LEVELS; i += NTHREADS) s_wt[i] = wt[i];
    __syncthreads();

    const vfloat4* __restrict__ x4 = (const vfloat4*)x;
    const vfloat4* __restrict__ y4 = (const vfloat4*)y;
    const int n4 = n >> 2;                 // N = 2^24, divisible by 4
    const int stride = NBLOCKS * NTHREADS; // 524288
    const int base = blockIdx.x * NTHREADS + threadIdx.x;

    float a0 = 0.f, a1 = 0.f;

    // n4 == 8 * stride for N = 2^24; process UNROLL strided slots per pass.
    if ((n4 % (UNROLL * stride)) == 0) {
        for (int i = base; i < n4; i += UNROLL * stride) {
            vfloat4 xs[UNROLL], ys[UNROLL];
            #pragma unroll
            for (int k = 0; k < UNROLL; ++k) {
                // nontemporal: bypass L2/L3 allocation for the streaming inputs
                xs[k] = __builtin_nontemporal_load(&x4[i + k * stride]);
                ys[k] = __builtin_nontemporal_load(&y4[i + k * stride]);
            }
            #pragma unroll
            for (int k = 0; k < UNROLL; ++k) {
                vfloat4 xv = xs[k], yv = ys[k];
                float w0 = s_wt[__float2int_rn(yv.x * 100.f)];
                float w1 = s_wt[__float2int_rn(yv.y * 100.f)];
                float w2 = s_wt[__float2int_rn(yv.z * 100.f)];
                float w3 = s_wt[__float2int_rn(yv.w * 100.f)];
                float d0 = xv.x - yv.x, d1 = xv.y - yv.y;
                float d2 = xv.z - yv.z, d3 = xv.w - yv.w;
                a0 += d0 * d0 * w0 + d2 * d2 * w2;
                a1 += d1 * d1 * w1 + d3 * d3 * w3;
            }
        }
    } else {
        for (int i = base; i < n4; i += stride) {
            vfloat4 xv = __builtin_nontemporal_load(&x4[i]);
            vfloat4 yv = __builtin_nontemporal_load(&y4[i]);
            float w0 = s_wt[__float2int_rn(yv.x * 100.f)];
            float w1 = s_wt[__float2int_rn(yv.y * 100.f)];
            float w2 = s_wt[__float2int_rn(yv.z * 100.f)];
            float w3 = s_wt[__float2int_rn(yv.w * 100.f)];
            float d0 = xv.x - yv.x, d1 = xv.y - yv.y;
            float d2 = xv.z - yv.z, d3 = xv.w - yv.w;
            a0 += d0 * d0 * w0 + d2 * d2 * w2;
            a1 += d1 * d1 * w1 + d3 * d3 * w3;
        }
    }

    float acc = a0 + a1;

    // wave-64 shuffle reduction
    #pragma unroll
    for (int off = 32; off > 0; off >>= 1)
        acc += __shfl_down(acc, off, 64);

    const int lane = threadIdx.x & 63;
    const int wave = threadIdx.x >> 6;
    if (lane == 0) s_red[wave] = acc;
    __syncthreads();
    if (threadIdx.x == 0) {
        float s = 0.f;
        #pragma unroll
        for (int w = 0; w < NTHREADS / 64; ++w) s += s_red[w];
        atomicAdd(out, s * inv_n);   // device-scope, safe across XCDs
    }
}

extern "C" void kernel_launch(void* const* d_in, const int* in_sizes, int n_in,
                              void* d_out, int out_size, void* d_ws, size_t ws_size,
                              hipStream_t stream) {
    const float* x  = (const float*)d_in[0];
    const float* y  = (const float*)d_in[1];
    const float* wt = (const float*)d_in[2];
    float* out = (float*)d_out;
    const int n = in_sizes[0];

    // d_out is poisoned to 0xAA before every timed launch; zero it on-stream
    // (graph-capturable) so the atomic accumulation starts from 0.
    (void)hipMemsetAsync(out, 0, sizeof(float), stream);
    wmse_fused<<<NBLOCKS, NTHREADS, 0, stream>>>(x, y, wt, out, n, 1.0f / (float)n);
}